// Round 7
// baseline (273.261 us; speedup 1.0000x reference)
//
#include <hip/hip_runtime.h>
#include <hip/hip_fp16.h>

// FNet Fourier mixing: out = Re(FFT(x, axis=1, norm="ortho")), x (8,4096,1024) fp32.
// Four-step FFT, 4096 = 64 x 64, pair-packed complex columns (z_p = x[:,2p] + i x[:,2p+1]).
// Round 10 = Round 9 resubmitted verbatim (R9 bench died to a container-acquisition
// infra failure before running; no kernel signal). Widen ONLY DRAM-touching segments:
//   pass1: 4 pairs/thread -> 2 KiB x-reads, 1 KiB u-writes; two-round transpose reusing
//          one 66 KB LDS buffer (2 blocks/CU unchanged).
//   pass2: 1024-thread blocks -> full-wave rows: 512 B u-reads, 1 KiB out-writes;
//          130 KB fp32 LDS (1 block/CU x 16 waves = same wave count as before).
// No precision change (all LDS fp32): absmax must stay 0.015625.
// Register radix-8x8 FFT64; fp16 intermediate in d_ws (scaled 1/64), k1-major.
// Fallback: round-2 fp32 kernels.

static constexpr int SEQ = 4096;
static constexpr int HID = 1024;

struct alignas(8)  h2x2 { __half2 a, b; };   // two packed complex fp16 values
struct alignas(16) h2x4 { h2x2 a, b; };      // four packed complex fp16 values

typedef float nv4 __attribute__((ext_vector_type(4)));   // native vec for NT builtins

__device__ __forceinline__ int rev4_3(int r) {
    return ((r & 3) << 4) | (r & 12) | ((r >> 4) & 3);
}

// ---------------- register radix-8 machinery ----------------

// 8-point complex DFT (forward, W8 = e^{-2*pi*i/8}), natural in, natural out.
__device__ __forceinline__ void fft8(float* xr, float* xi) {
    const float C = 0.70710678118654752f;
    float ar[8], ai[8];
    ar[0] = xr[0] + xr[4];  ai[0] = xi[0] + xi[4];
    ar[1] = xr[0] - xr[4];  ai[1] = xi[0] - xi[4];
    ar[2] = xr[2] + xr[6];  ai[2] = xi[2] + xi[6];
    ar[3] = xr[2] - xr[6];  ai[3] = xi[2] - xi[6];
    ar[4] = xr[1] + xr[5];  ai[4] = xi[1] + xi[5];
    ar[5] = xr[1] - xr[5];  ai[5] = xi[1] - xi[5];
    ar[6] = xr[3] + xr[7];  ai[6] = xi[3] + xi[7];
    ar[7] = xr[3] - xr[7];  ai[7] = xi[3] - xi[7];
    float br[8], bi[8];
    br[0] = ar[0] + ar[2];  bi[0] = ai[0] + ai[2];
    br[2] = ar[0] - ar[2];  bi[2] = ai[0] - ai[2];
    br[1] = ar[1] + ai[3];  bi[1] = ai[1] - ar[3];
    br[3] = ar[1] - ai[3];  bi[3] = ai[1] + ar[3];
    br[4] = ar[4] + ar[6];  bi[4] = ai[4] + ai[6];
    br[6] = ar[4] - ar[6];  bi[6] = ai[4] - ai[6];
    br[5] = ar[5] + ai[7];  bi[5] = ai[5] - ar[7];
    br[7] = ar[5] - ai[7];  bi[7] = ai[5] + ar[7];
    const float t0r = br[4],                 t0i = bi[4];
    const float t1r = C * (br[5] + bi[5]),   t1i = C * (bi[5] - br[5]);
    const float t2r = bi[6],                 t2i = -br[6];
    const float t3r = C * (bi[7] - br[7]),   t3i = -C * (br[7] + bi[7]);
    xr[0] = br[0] + t0r;  xi[0] = bi[0] + t0i;
    xr[4] = br[0] - t0r;  xi[4] = bi[0] - t0i;
    xr[1] = br[1] + t1r;  xi[1] = bi[1] + t1i;
    xr[5] = br[1] - t1r;  xi[5] = bi[1] - t1i;
    xr[2] = br[2] + t2r;  xi[2] = bi[2] + t2i;
    xr[6] = br[2] - t2r;  xi[6] = bi[2] - t2i;
    xr[3] = br[3] + t3r;  xi[3] = bi[3] + t3i;
    xr[7] = br[3] - t3r;  xi[7] = bi[3] - t3i;
}

// x[k] *= W^k for k=1..7, W = wc + i*ws (fp32 recurrence).
__device__ __forceinline__ void twiddle_chain(float* xr, float* xi,
                                              const float wc, const float ws) {
    float cr = wc, ci = ws;
    #pragma unroll
    for (int k = 1; k < 8; ++k) {
        const float tr = xr[k] * cr - xi[k] * ci;
        xi[k] = xr[k] * ci + xi[k] * cr;
        xr[k] = tr;
        if (k < 7) {
            const float nr = cr * wc - ci * ws;
            const float ni = cr * ws + ci * wc;
            cr = nr;  ci = ni;
        }
    }
}

// ---------------- fp16-intermediate path (radix-8x8, wide segments) ----------------
// u layout (k1-major): __half2 u[8][4096][512];
// u[b][64*k1+n2][p] = (1/64) W4096^{n2 k1} FFT64(z_p)[k1],  z_p[n1] over rows n2+64*n1.

// grid = 8 b * 64 n2 * 2 pc (256 pair-cols each); 512 thr; 66 KB LDS, 2 blocks/CU.
// Wave reads 2 KiB x segments, writes 1 KiB u segments (h2x4/lane).
__global__ __launch_bounds__(512, 4) void fft_pass1_x4(const float* __restrict__ x,
                                                       __half2* __restrict__ u) {
    __shared__ float4 zs[64 * 65];            // transpose scratch, reused both rounds
    const int t  = threadIdx.x;
    const int pc = blockIdx.x & 1;
    const int n2 = (blockIdx.x >> 1) & 63;
    const int b  = blockIdx.x >> 7;
    const int c  = t & 63;                    // float8-slot (4 pairs)
    const int q  = t >> 6;                    // wave id == n1 mod 8

    const float* xb = x + (size_t)b * SEQ * HID + (size_t)(pc * 512 + 8 * c);
    nv4 rawA[8], rawB[8];
    #pragma unroll
    for (int a = 0; a < 8; ++a) {             // n1 = 8a + q, row = n2 + 64*n1
        const float* rp = xb + (size_t)(n2 + 64 * (8 * a + q)) * HID;
        rawA[a] = __builtin_nontemporal_load((const nv4*)rp);
        rawB[a] = __builtin_nontemporal_load((const nv4*)(rp + 4));
    }

    float wq_s, wq_c;
    __sincosf(-0.09817477042468103f * (float)q, &wq_s, &wq_c);   // -2pi q/64
    const float tw = -1.5339807878856412e-3f; // -2pi/4096
    float w0c0, w0s0, wsc, wss;
    __sincosf(tw * (float)(n2 * q), &w0s0, &w0c0);
    __sincosf(tw * (float)(n2 * 8), &wss, &wsc);
    const float sc = 0.015625f;               // 1/64
    w0c0 *= sc;  w0s0 *= sc;

    h2x2 o0[8], o1[8];
    #pragma unroll
    for (int g = 0; g < 2; ++g) {             // round g: pairs 4c+2g, 4c+2g+1
        float fr0[8], fi0[8], fr1[8], fi1[8];
        #pragma unroll
        for (int a = 0; a < 8; ++a) {
            const nv4 v = g ? rawB[a] : rawA[a];
            fr0[a] = v.x;  fi0[a] = v.y;  fr1[a] = v.z;  fi1[a] = v.w;
        }
        fft8(fr0, fi0);  twiddle_chain(fr0, fi0, wq_c, wq_s);
        fft8(fr1, fi1);  twiddle_chain(fr1, fi1, wq_c, wq_s);

        #pragma unroll
        for (int k = 0; k < 8; ++k)
            zs[(k * 8 + q) * 65 + c] = make_float4(fr0[k], fi0[k], fr1[k], fi1[k]);
        __syncthreads();
        float4 rw[8];
        #pragma unroll
        for (int r = 0; r < 8; ++r) rw[r] = zs[(q * 8 + r) * 65 + c];
        __syncthreads();                      // zs free for next round

        #pragma unroll
        for (int a = 0; a < 8; ++a) { fr0[a] = rw[a].x; fi0[a] = rw[a].y; }
        fft8(fr0, fi0);                       // X[q + 8*kh] in slot kh, col 2g
        #pragma unroll
        for (int a = 0; a < 8; ++a) { fr1[a] = rw[a].z; fi1[a] = rw[a].w; }
        fft8(fr1, fi1);                       // col 2g+1

        float w0c = w0c0, w0s = w0s0;
        h2x2* oo = g ? o1 : o0;
        #pragma unroll
        for (int kh = 0; kh < 8; ++kh) {
            oo[kh].a = __floats2half2_rn(fr0[kh] * w0c - fi0[kh] * w0s,
                                         fr0[kh] * w0s + fi0[kh] * w0c);
            oo[kh].b = __floats2half2_rn(fr1[kh] * w0c - fi1[kh] * w0s,
                                         fr1[kh] * w0s + fi1[kh] * w0c);
            if (kh < 7) {
                const float nc = w0c * wsc - w0s * wss;
                const float ns = w0c * wss + w0s * wsc;
                w0c = nc;  w0s = ns;
            }
        }
    }

    // k1-major: row = 64*k1 + n2, k1 = q + 8*kh -> base row 64*q + n2, +512 rows per kh.
    // Pairs 4c..4c+3 -> 16 B/lane, contiguous 1 KiB per wave.
    __half2* ub = u + (size_t)b * SEQ * 512 + (size_t)(64 * q + n2) * 512 + pc * 256 + 4 * c;
    #pragma unroll
    for (int kh = 0; kh < 8; ++kh) {
        h2x4 o;  o.a = o0[kh];  o.b = o1[kh];
        *(h2x4*)(ub + (size_t)kh * (512 * 512)) = o;
    }
}

// grid = 8 b * 128: idx<124 -> paired {k1, 64-k1}, 4 chunks of 128 pairs;
// idx>=124 -> self-paired k1 in {0,32}, 2 chunks of 256 pairs.
// 1024 thr; 130 KB fp32 LDS -> 1 block/CU x 16 waves (same wave count as before).
// Full-wave rows: 512 B u-reads, 1 KiB out-writes.
__global__ __launch_bounds__(1024, 4) void fft_pass2_x4(const __half2* __restrict__ u,
                                                        float* __restrict__ out) {
    __shared__ float4 vs[8320];               // paired: [128 rows][pitch 65]; special: [64][129]
    const int t   = threadIdx.x;
    const int b   = blockIdx.x >> 7;
    const int idx = blockIdx.x & 127;
    const __half2* ub = u   + (size_t)b * SEQ * 512;
    float*         ob = out + (size_t)b * SEQ * HID;
    const float scale = 0.5f;                 // total 1/128 = (1/64 pass1) * this
    float fr0[8], fi0[8], fr1[8], fi1[8];

    if (idx < 124) {
        const int k1 = 1 + (idx >> 2);        // 1..31
        const int pc = idx & 3;               // 128-pair chunk
        const int ab = t >> 9;                // 0 -> k1, 1 -> 64-k1
        const int q  = (t >> 6) & 7;          // residue n2 mod 8
        const int c  = t & 63;                // h2x2 column (2 pairs)
        const int k1sel = ab ? 64 - k1 : k1;
        const int p  = pc * 128 + 2 * c;      // pair index
        const __half2* up = ub + (size_t)(64 * k1sel) * 512 + p;
        h2x2 raw[8];
        #pragma unroll
        for (int a = 0; a < 8; ++a)           // n2 = 8a + q (contiguous slab)
            raw[a] = *(const h2x2*)(up + (size_t)(8 * a + q) * 512);

        float wq_s, wq_c;
        __sincosf(-0.09817477042468103f * (float)q, &wq_s, &wq_c);
        #pragma unroll
        for (int a = 0; a < 8; ++a) {
            const float2 v = __half22float2(raw[a].a);
            fr0[a] = v.x;  fi0[a] = v.y;
        }
        fft8(fr0, fi0);
        twiddle_chain(fr0, fi0, wq_c, wq_s);
        #pragma unroll
        for (int a = 0; a < 8; ++a) {
            const float2 v = __half22float2(raw[a].b);
            fr1[a] = v.x;  fi1[a] = v.y;
        }
        fft8(fr1, fi1);
        twiddle_chain(fr1, fi1, wq_c, wq_s);

        const int base = ab * 64;
        #pragma unroll
        for (int k = 0; k < 8; ++k)
            vs[(base + k * 8 + q) * 65 + c] = make_float4(fr0[k], fi0[k], fr1[k], fi1[k]);
        __syncthreads();
        float4 rw[8];
        #pragma unroll
        for (int r = 0; r < 8; ++r) rw[r] = vs[(base + q * 8 + r) * 65 + c];
        #pragma unroll
        for (int a = 0; a < 8; ++a) { fr0[a] = rw[a].x; fi0[a] = rw[a].y; }
        fft8(fr0, fi0);                       // V_ab[q + 8 kh], col 0
        #pragma unroll
        for (int a = 0; a < 8; ++a) { fr1[a] = rw[a].z; fi1[a] = rw[a].w; }
        fft8(fr1, fi1);                       // col 1
        __syncthreads();
        #pragma unroll
        for (int k = 0; k < 8; ++k)
            vs[(base + k * 8 + q) * 65 + c] = make_float4(fr0[k], fi0[k], fr1[k], fi1[k]);
        __syncthreads();

        // out row k1sel + 64*k2: own V[k2] + partner V_{1-ab}[63-k2]
        float* op = ob + (size_t)k1sel * HID + (size_t)(pc * 256 + 4 * c);
        #pragma unroll
        for (int kh = 0; kh < 8; ++kh) {
            const float4 pv = vs[((64 - base) + (7 - kh) * 8 + (7 - q)) * 65 + c];
            const int k2 = q + 8 * kh;
            nv4 o;
            o.x = (fr0[kh] + pv.x) * scale;
            o.y = (fi0[kh] + pv.y) * scale;
            o.z = (fr1[kh] + pv.z) * scale;
            o.w = (fi1[kh] + pv.w) * scale;
            __builtin_nontemporal_store(o, (nv4*)(op + (size_t)(64 * k2) * HID));
        }
    } else {
        const int s  = idx - 124;
        const int k1 = (s >> 1) * 32;         // 0 or 32
        const int pc = s & 1;                 // 256-pair chunk
        const int q  = t >> 7;
        const int c  = t & 127;               // h2x2 column (2 pairs)
        const int p  = pc * 256 + 2 * c;
        const __half2* up = ub + (size_t)(64 * k1) * 512 + p;
        h2x2 raw[8];
        #pragma unroll
        for (int a = 0; a < 8; ++a)
            raw[a] = *(const h2x2*)(up + (size_t)(8 * a + q) * 512);

        float wq_s, wq_c;
        __sincosf(-0.09817477042468103f * (float)q, &wq_s, &wq_c);
        #pragma unroll
        for (int a = 0; a < 8; ++a) {
            const float2 v = __half22float2(raw[a].a);
            fr0[a] = v.x;  fi0[a] = v.y;
        }
        fft8(fr0, fi0);
        twiddle_chain(fr0, fi0, wq_c, wq_s);
        #pragma unroll
        for (int a = 0; a < 8; ++a) {
            const float2 v = __half22float2(raw[a].b);
            fr1[a] = v.x;  fi1[a] = v.y;
        }
        fft8(fr1, fi1);
        twiddle_chain(fr1, fi1, wq_c, wq_s);

        #pragma unroll
        for (int k = 0; k < 8; ++k)
            vs[(k * 8 + q) * 129 + c] = make_float4(fr0[k], fi0[k], fr1[k], fi1[k]);
        __syncthreads();
        float4 rw[8];
        #pragma unroll
        for (int r = 0; r < 8; ++r) rw[r] = vs[(q * 8 + r) * 129 + c];
        #pragma unroll
        for (int a = 0; a < 8; ++a) { fr0[a] = rw[a].x; fi0[a] = rw[a].y; }
        fft8(fr0, fi0);
        #pragma unroll
        for (int a = 0; a < 8; ++a) { fr1[a] = rw[a].z; fi1[a] = rw[a].w; }
        fft8(fr1, fi1);
        __syncthreads();
        #pragma unroll
        for (int k = 0; k < 8; ++k)
            vs[(k * 8 + q) * 129 + c] = make_float4(fr0[k], fi0[k], fr1[k], fi1[k]);
        __syncthreads();

        // partner index: k1==0 -> (64-k2)%64, k1==32 -> 63-k2
        const int q2 = (k1 == 0) ? ((8 - q) & 7) : (7 - q);
        float* op = ob + (size_t)k1 * HID + (size_t)(pc * 512 + 4 * c);
        #pragma unroll
        for (int kh = 0; kh < 8; ++kh) {
            const int kh2 = (k1 == 0 && q == 0) ? ((8 - kh) & 7) : (7 - kh);
            const float4 pv = vs[(kh2 * 8 + q2) * 129 + c];
            const int k2 = q + 8 * kh;
            nv4 o;
            o.x = (fr0[kh] + pv.x) * scale;
            o.y = (fi0[kh] + pv.y) * scale;
            o.z = (fr1[kh] + pv.z) * scale;
            o.w = (fi1[kh] + pv.w) * scale;
            __builtin_nontemporal_store(o, (nv4*)(op + (size_t)(64 * k2) * HID));
        }
    }
}

// ---------------- fp32 in-place fallback (round-2 kernels, unchanged) ----------------

template <int MC>
__device__ __forceinline__ void fft64_lds(float* re, float* im, int off, int stride, int mbase) {
    #pragma unroll
    for (int s = 0; s < 3; ++s) {
        const int L = 1 << (2 * s);
        const float ang = -6.283185307179586f / (float)(4 * L);
        #pragma unroll
        for (int mi = 0; mi < MC; ++mi) {
            const int m  = mbase + mi;
            const int j  = m & (L - 1);
            const int i0 = ((m >> (2 * s)) << (2 * s + 2)) + j;
            const int a0 = (i0        ) * stride + off;
            const int a1 = (i0 +     L) * stride + off;
            const int a2 = (i0 + 2 * L) * stride + off;
            const int a3 = (i0 + 3 * L) * stride + off;
            const float e0x = re[a0], e0y = im[a0];
            const float e1x = re[a1], e1y = im[a1];
            const float e2x = re[a2], e2y = im[a2];
            const float e3x = re[a3], e3y = im[a3];
            float w1s, w1c;
            __sincosf(ang * (float)j, &w1s, &w1c);
            const float w2c = w1c * w1c - w1s * w1s, w2s = 2.f * w1c * w1s;
            const float w3c = w2c * w1c - w2s * w1s, w3s = w2c * w1s + w2s * w1c;
            const float t1x = e1x * w1c - e1y * w1s, t1y = e1x * w1s + e1y * w1c;
            const float t2x = e2x * w2c - e2y * w2s, t2y = e2x * w2s + e2y * w2c;
            const float t3x = e3x * w3c - e3y * w3s, t3y = e3x * w3s + e3y * w3c;
            const float a02x = e0x + t2x, a02y = e0y + t2y;
            const float s02x = e0x - t2x, s02y = e0y - t2y;
            const float a13x = t1x + t3x, a13y = t1y + t3y;
            const float s13x = t1x - t3x, s13y = t1y - t3y;
            re[a0] = a02x + a13x;  im[a0] = a02y + a13y;
            re[a1] = s02x + s13y;  im[a1] = s02y - s13x;
            re[a2] = a02x - a13x;  im[a2] = a02y - a13y;
            re[a3] = s02x - s13y;  im[a3] = s02y + s13x;
        }
        __syncthreads();
    }
}

__global__ __launch_bounds__(256) void fft_pass1(const float* __restrict__ x,
                                                 float* __restrict__ out) {
    __shared__ float sre[64 * 65];
    __shared__ float sim[64 * 65];
    const int t  = threadIdx.x;
    const int pc = blockIdx.x & 7;
    const int n2 = (blockIdx.x >> 3) & 63;
    const int b  = blockIdx.x >> 9;
    const float* xb = x   + (size_t)b * SEQ * HID + pc * 128;
    float*       ob = out + (size_t)b * SEQ * HID + pc * 128;

    const int c  = t & 31;
    const int r0 = t >> 5;
    #pragma unroll
    for (int i = 0; i < 8; ++i) {
        const int r  = r0 + 8 * i;
        const float4 f = *(const float4*)(xb + (size_t)(n2 + 64 * r) * HID + 4 * c);
        const int rr = rev4_3(r);
        sre[rr * 65 + 2 * c]     = f.x;  sim[rr * 65 + 2 * c]     = f.y;
        sre[rr * 65 + 2 * c + 1] = f.z;  sim[rr * 65 + 2 * c + 1] = f.w;
    }
    __syncthreads();

    fft64_lds<4>(sre, sim, t & 63, 65, 4 * (t >> 6));

    const float tw = -1.5339807878856412e-3f;
    #pragma unroll
    for (int i = 0; i < 8; ++i) {
        const int k1 = r0 + 8 * i;
        float ws, wc;
        __sincosf(tw * (float)(n2 * k1), &ws, &wc);
        const float ar = sre[k1 * 65 + 2 * c],     ai = sim[k1 * 65 + 2 * c];
        const float br = sre[k1 * 65 + 2 * c + 1], bi = sim[k1 * 65 + 2 * c + 1];
        float4 f;
        f.x = ar * wc - ai * ws;  f.y = ar * ws + ai * wc;
        f.z = br * wc - bi * ws;  f.w = br * ws + bi * wc;
        *(float4*)(ob + (size_t)(64 * n2 + k1) * HID + 4 * c) = f;
    }
}

__global__ __launch_bounds__(256) void fft_pass2(float* out) {
    __shared__ float lds[8448];
    const int t   = threadIdx.x;
    const int b   = blockIdx.x >> 9;
    const int idx = blockIdx.x & 511;
    float* ob = out + (size_t)b * SEQ * HID;
    const float scale = 1.0f / 128.0f;

    if (idx < 496) {
        const int k1 = 1 + (idx >> 4);
        const int pc = idx & 15;
        float* are = lds;          float* aim = lds + 2112;
        float* bre = lds + 4224;   float* bim = lds + 6336;
        const int c  = t & 15;
        const int rg = t >> 4;
        #pragma unroll
        for (int i = 0; i < 4; ++i) {
            const int n2 = rg + 16 * i;
            const int rr = rev4_3(n2);
            const float4 fa = *(const float4*)(ob + (size_t)(64 * n2 + k1)      * HID + pc * 64 + 4 * c);
            const float4 fb = *(const float4*)(ob + (size_t)(64 * n2 + 64 - k1) * HID + pc * 64 + 4 * c);
            are[rr * 33 + 2 * c]     = fa.x;  aim[rr * 33 + 2 * c]     = fa.y;
            are[rr * 33 + 2 * c + 1] = fa.z;  aim[rr * 33 + 2 * c + 1] = fa.w;
            bre[rr * 33 + 2 * c]     = fb.x;  bim[rr * 33 + 2 * c]     = fb.y;
            bre[rr * 33 + 2 * c + 1] = fb.z;  bim[rr * 33 + 2 * c + 1] = fb.w;
        }
        __syncthreads();

        const int lane = t & 63;
        float* fre = lds + 4224 * (lane >> 5);
        fft64_lds<4>(fre, fre + 2112, lane & 31, 33, 4 * (t >> 6));

        #pragma unroll
        for (int i = 0; i < 4; ++i) {
            const int k2 = rg + 16 * i;
            const int q  = 63 - k2;
            float4 f, g;
            f.x = (are[k2 * 33 + 2 * c]     + bre[q * 33 + 2 * c])     * scale;
            f.y = (aim[k2 * 33 + 2 * c]     + bim[q * 33 + 2 * c])     * scale;
            f.z = (are[k2 * 33 + 2 * c + 1] + bre[q * 33 + 2 * c + 1]) * scale;
            f.w = (aim[k2 * 33 + 2 * c + 1] + bim[q * 33 + 2 * c + 1]) * scale;
            *(float4*)(ob + (size_t)(k1 + 64 * k2)      * HID + pc * 64 + 4 * c) = f;
            g.x = (bre[k2 * 33 + 2 * c]     + are[q * 33 + 2 * c])     * scale;
            g.y = (bim[k2 * 33 + 2 * c]     + aim[q * 33 + 2 * c])     * scale;
            g.z = (bre[k2 * 33 + 2 * c + 1] + are[q * 33 + 2 * c + 1]) * scale;
            g.w = (bim[k2 * 33 + 2 * c + 1] + aim[q * 33 + 2 * c + 1]) * scale;
            *(float4*)(ob + (size_t)(64 - k1 + 64 * k2) * HID + pc * 64 + 4 * c) = g;
        }
    } else {
        const int s  = idx - 496;
        const int k1 = (s >> 3) * 32;
        const int pc = s & 7;
        float* sre = lds;
        float* sim = lds + 4160;
        const int c  = t & 31;
        const int rg = t >> 5;
        #pragma unroll
        for (int i = 0; i < 8; ++i) {
            const int n2 = rg + 8 * i;
            const int rr = rev4_3(n2);
            const float4 f = *(const float4*)(ob + (size_t)(64 * n2 + k1) * HID + pc * 128 + 4 * c);
            sre[rr * 65 + 2 * c]     = f.x;  sim[rr * 65 + 2 * c]     = f.y;
            sre[rr * 65 + 2 * c + 1] = f.z;  sim[rr * 65 + 2 * c + 1] = f.w;
        }
        __syncthreads();

        fft64_lds<4>(sre, sim, t & 63, 65, 4 * (t >> 6));

        #pragma unroll
        for (int i = 0; i < 8; ++i) {
            const int k2 = rg + 8 * i;
            const int q  = (k1 == 0) ? ((64 - k2) & 63) : (63 - k2);
            float4 f;
            f.x = (sre[k2 * 65 + 2 * c]     + sre[q * 65 + 2 * c])     * scale;
            f.y = (sim[k2 * 65 + 2 * c]     + sim[q * 65 + 2 * c])     * scale;
            f.z = (sre[k2 * 65 + 2 * c + 1] + sre[q * 65 + 2 * c + 1]) * scale;
            f.w = (sim[k2 * 65 + 2 * c + 1] + sim[q * 65 + 2 * c + 1]) * scale;
            *(float4*)(ob + (size_t)(k1 + 64 * k2) * HID + pc * 128 + 4 * c) = f;
        }
    }
}

extern "C" void kernel_launch(void* const* d_in, const int* in_sizes, int n_in,
                              void* d_out, int out_size, void* d_ws, size_t ws_size,
                              hipStream_t stream) {
    const float* x = (const float*)d_in[0];
    float* out = (float*)d_out;
    const size_t need = (size_t)8 * SEQ * 512 * sizeof(__half2);   // 64 MiB
    if (ws_size >= need) {
        __half2* u = (__half2*)d_ws;
        fft_pass1_x4<<<dim3(8 * 64 * 2), dim3(512), 0, stream>>>(x, u);
        fft_pass2_x4<<<dim3(8 * 128), dim3(1024), 0, stream>>>(u, out);
    } else {
        fft_pass1<<<dim3(8 * 64 * 8), dim3(256), 0, stream>>>(x, out);
        fft_pass2<<<dim3(8 * 512), dim3(256), 0, stream>>>(out);
    }
}

// Round 8
// 241.247 us; speedup vs baseline: 1.1327x; 1.1327x over previous
//
#include <hip/hip_runtime.h>
#include <hip/hip_fp16.h>

// FNet Fourier mixing: out = Re(FFT(x, axis=1, norm="ortho")), x (8,4096,1024) fp32.
// Four-step FFT, 4096 = 64 x 64, pair-packed complex columns (z_p = x[:,2p] + i x[:,2p+1]).
// Round 11: REVERT to the Round-5 kernel (best verified: 239.8 us). Round-7's x4
// widening regressed +33 us: pass2 at 130KB LDS/1024thr -> 1 block/CU (barrier stalls
// whole CU), pass1 4 barriers + ~64 extra VGPRs. Lesson: segment-widening lever is
// exhausted at 1KiB-read/512B-write with 2 blocks/CU; u is L3-resident (layout-neutral);
// compute organization is not the limiter. This config is the measured optimum.
//   pass1: 2 col-pairs/thread, 1KiB x-reads (NT), 512B u-writes, 1 barrier, 65KB LDS.
//   pass2: 512thr, 256-512B u-reads, 512B-1KiB out-writes (NT), 66KB LDS, 2 blocks/CU.
// Register radix-8x8 FFT64; fp16 intermediate in d_ws (scaled 1/64), k1-major.
// Fallback: round-2 fp32 kernels.

static constexpr int SEQ = 4096;
static constexpr int HID = 1024;

struct alignas(8) h2x2 { __half2 a, b; };   // two packed complex fp16 values

typedef float nv4 __attribute__((ext_vector_type(4)));   // native vec for NT builtins

__device__ __forceinline__ int rev4_3(int r) {
    return ((r & 3) << 4) | (r & 12) | ((r >> 4) & 3);
}

// ---------------- register radix-8 machinery ----------------

// 8-point complex DFT (forward, W8 = e^{-2*pi*i/8}), natural in, natural out.
__device__ __forceinline__ void fft8(float* xr, float* xi) {
    const float C = 0.70710678118654752f;
    float ar[8], ai[8];
    ar[0] = xr[0] + xr[4];  ai[0] = xi[0] + xi[4];
    ar[1] = xr[0] - xr[4];  ai[1] = xi[0] - xi[4];
    ar[2] = xr[2] + xr[6];  ai[2] = xi[2] + xi[6];
    ar[3] = xr[2] - xr[6];  ai[3] = xi[2] - xi[6];
    ar[4] = xr[1] + xr[5];  ai[4] = xi[1] + xi[5];
    ar[5] = xr[1] - xr[5];  ai[5] = xi[1] - xi[5];
    ar[6] = xr[3] + xr[7];  ai[6] = xi[3] + xi[7];
    ar[7] = xr[3] - xr[7];  ai[7] = xi[3] - xi[7];
    float br[8], bi[8];
    br[0] = ar[0] + ar[2];  bi[0] = ai[0] + ai[2];
    br[2] = ar[0] - ar[2];  bi[2] = ai[0] - ai[2];
    br[1] = ar[1] + ai[3];  bi[1] = ai[1] - ar[3];
    br[3] = ar[1] - ai[3];  bi[3] = ai[1] + ar[3];
    br[4] = ar[4] + ar[6];  bi[4] = ai[4] + ai[6];
    br[6] = ar[4] - ar[6];  bi[6] = ai[4] - ai[6];
    br[5] = ar[5] + ai[7];  bi[5] = ai[5] - ar[7];
    br[7] = ar[5] - ai[7];  bi[7] = ai[5] + ar[7];
    const float t0r = br[4],                 t0i = bi[4];
    const float t1r = C * (br[5] + bi[5]),   t1i = C * (bi[5] - br[5]);
    const float t2r = bi[6],                 t2i = -br[6];
    const float t3r = C * (bi[7] - br[7]),   t3i = -C * (br[7] + bi[7]);
    xr[0] = br[0] + t0r;  xi[0] = bi[0] + t0i;
    xr[4] = br[0] - t0r;  xi[4] = bi[0] - t0i;
    xr[1] = br[1] + t1r;  xi[1] = bi[1] + t1i;
    xr[5] = br[1] - t1r;  xi[5] = bi[1] - t1i;
    xr[2] = br[2] + t2r;  xi[2] = bi[2] + t2i;
    xr[6] = br[2] - t2r;  xi[6] = bi[2] - t2i;
    xr[3] = br[3] + t3r;  xi[3] = bi[3] + t3i;
    xr[7] = br[3] - t3r;  xi[7] = bi[3] - t3i;
}

// x[k] *= W^k for k=1..7, W = wc + i*ws (fp32 recurrence).
__device__ __forceinline__ void twiddle_chain(float* xr, float* xi,
                                              const float wc, const float ws) {
    float cr = wc, ci = ws;
    #pragma unroll
    for (int k = 1; k < 8; ++k) {
        const float tr = xr[k] * cr - xi[k] * ci;
        xi[k] = xr[k] * ci + xi[k] * cr;
        xr[k] = tr;
        if (k < 7) {
            const float nr = cr * wc - ci * ws;
            const float ni = cr * ws + ci * wc;
            cr = nr;  ci = ni;
        }
    }
}

// ---------------- fp16-intermediate path (radix-8x8, 2 col-pairs/thread) ----------------
// u layout (k1-major): __half2 u[8][4096][512];
// u[b][64*k1+n2][p] = (1/64) W4096^{n2 k1} FFT64(z_p)[k1],  z_p[n1] over rows n2+64*n1.

// grid = 8 b * 64 n2 * 4 pc (128 pair-cols each); 512 thr; ~65 KB LDS, 2 blocks/CU.
// Wave reads 1 KiB input segments, writes 512 B u segments.
__global__ __launch_bounds__(512, 4) void fft_pass1_x2(const float* __restrict__ x,
                                                       __half2* __restrict__ u) {
    __shared__ float4 zs[64 * 65];            // row = k*8+q (64), col c (64), +1 pad
    const int t  = threadIdx.x;
    const int pc = blockIdx.x & 3;
    const int n2 = (blockIdx.x >> 2) & 63;
    const int b  = blockIdx.x >> 8;
    const int c  = t & 63;                    // float4 column (2 pairs)
    const int q  = t >> 6;                    // wave id == n1 mod 8

    const float* xb = x + (size_t)b * SEQ * HID + (size_t)(pc * 256 + 4 * c);
    nv4 raw[8];
    #pragma unroll
    for (int a = 0; a < 8; ++a)               // n1 = 8a + q, row = n2 + 64*n1
        raw[a] = __builtin_nontemporal_load(
            (const nv4*)(xb + (size_t)(n2 + 64 * (8 * a + q)) * HID));

    float wq_s, wq_c;
    __sincosf(-0.09817477042468103f * (float)q, &wq_s, &wq_c);   // -2pi q/64

    float fr0[8], fi0[8], fr1[8], fi1[8];
    #pragma unroll
    for (int a = 0; a < 8; ++a) { fr0[a] = raw[a].x; fi0[a] = raw[a].y; }
    fft8(fr0, fi0);
    twiddle_chain(fr0, fi0, wq_c, wq_s);
    #pragma unroll
    for (int a = 0; a < 8; ++a) { fr1[a] = raw[a].z; fi1[a] = raw[a].w; }
    fft8(fr1, fi1);
    twiddle_chain(fr1, fi1, wq_c, wq_s);

    #pragma unroll
    for (int k = 0; k < 8; ++k)
        zs[(k * 8 + q) * 65 + c] = make_float4(fr0[k], fi0[k], fr1[k], fi1[k]);
    __syncthreads();
    float4 rw[8];
    #pragma unroll
    for (int r = 0; r < 8; ++r) rw[r] = zs[(q * 8 + r) * 65 + c];

    #pragma unroll
    for (int a = 0; a < 8; ++a) { fr0[a] = rw[a].x; fi0[a] = rw[a].y; }
    fft8(fr0, fi0);                           // X[q + 8*kh] in slot kh, col 0
    #pragma unroll
    for (int a = 0; a < 8; ++a) { fr1[a] = rw[a].z; fi1[a] = rw[a].w; }
    fft8(fr1, fi1);                           // col 1

    const float tw = -1.5339807878856412e-3f; // -2pi/4096
    float w0c, w0s, wsc, wss;
    __sincosf(tw * (float)(n2 * q), &w0s, &w0c);
    __sincosf(tw * (float)(n2 * 8), &wss, &wsc);
    const float sc = 0.015625f;
    w0c *= sc;  w0s *= sc;
    // k1-major: row = 64*k1 + n2, k1 = q + 8*kh -> base row 64*q + n2, +512 rows per kh
    __half2* ub = u + (size_t)b * SEQ * 512 + (size_t)(64 * q + n2) * 512 + pc * 128 + 2 * c;
    #pragma unroll
    for (int kh = 0; kh < 8; ++kh) {
        h2x2 o;
        o.a = __floats2half2_rn(fr0[kh] * w0c - fi0[kh] * w0s,
                                fr0[kh] * w0s + fi0[kh] * w0c);
        o.b = __floats2half2_rn(fr1[kh] * w0c - fi1[kh] * w0s,
                                fr1[kh] * w0s + fi1[kh] * w0c);
        *(h2x2*)(ub + (size_t)kh * (512 * 512)) = o;
        if (kh < 7) {
            const float nc = w0c * wsc - w0s * wss;
            const float ns = w0c * wss + w0s * wsc;
            w0c = nc;  w0s = ns;
        }
    }
}

// grid = 8 b * 256: idx<248 -> paired {k1, 64-k1}, 8 chunks of 64 pairs;
// idx>=248 -> self-paired k1 in {0,32}, 4 chunks of 128 pairs. 512 thr; ~66 KB LDS.
// u-reads walk one contiguous 128KiB slab per k1.
__global__ __launch_bounds__(512, 4) void fft_pass2_x2(const __half2* __restrict__ u,
                                                       float* __restrict__ out) {
    __shared__ float4 vs[128 * 33];           // paired: [slab(2)*64 rows][c(32)] +1 pad
    const int t   = threadIdx.x;
    const int b   = blockIdx.x >> 8;
    const int idx = blockIdx.x & 255;
    const __half2* ub = u   + (size_t)b * SEQ * 512;
    float*         ob = out + (size_t)b * SEQ * HID;
    const float scale = 0.5f;                 // total 1/128 = (1/64 pass1) * this
    float fr0[8], fi0[8], fr1[8], fi1[8];

    if (idx < 248) {
        const int k1 = 1 + (idx >> 3);        // 1..31
        const int pc = idx & 7;               // 64-pair chunk
        const int ab = t >> 8;                // 0 -> k1, 1 -> 64-k1
        const int q  = (t >> 5) & 7;          // residue n2 mod 8
        const int c  = t & 31;                // h2x2 column (2 pairs)
        const int k1sel = ab ? 64 - k1 : k1;
        const int p  = pc * 64 + 2 * c;       // pair index
        // k1-major: rows 64*k1sel + (8a+q) -- contiguous slab
        const __half2* up = ub + (size_t)(64 * k1sel) * 512 + p;
        h2x2 raw[8];
        #pragma unroll
        for (int a = 0; a < 8; ++a)           // n2 = 8a + q
            raw[a] = *(const h2x2*)(up + (size_t)(8 * a + q) * 512);

        float wq_s, wq_c;
        __sincosf(-0.09817477042468103f * (float)q, &wq_s, &wq_c);
        #pragma unroll
        for (int a = 0; a < 8; ++a) {
            const float2 v = __half22float2(raw[a].a);
            fr0[a] = v.x;  fi0[a] = v.y;
        }
        fft8(fr0, fi0);
        twiddle_chain(fr0, fi0, wq_c, wq_s);
        #pragma unroll
        for (int a = 0; a < 8; ++a) {
            const float2 v = __half22float2(raw[a].b);
            fr1[a] = v.x;  fi1[a] = v.y;
        }
        fft8(fr1, fi1);
        twiddle_chain(fr1, fi1, wq_c, wq_s);

        const int base = ab * 64;
        #pragma unroll
        for (int k = 0; k < 8; ++k)
            vs[(base + k * 8 + q) * 33 + c] = make_float4(fr0[k], fi0[k], fr1[k], fi1[k]);
        __syncthreads();
        float4 rw[8];
        #pragma unroll
        for (int r = 0; r < 8; ++r) rw[r] = vs[(base + q * 8 + r) * 33 + c];
        #pragma unroll
        for (int a = 0; a < 8; ++a) { fr0[a] = rw[a].x; fi0[a] = rw[a].y; }
        fft8(fr0, fi0);                       // V_ab[q + 8 kh], col 0
        #pragma unroll
        for (int a = 0; a < 8; ++a) { fr1[a] = rw[a].z; fi1[a] = rw[a].w; }
        fft8(fr1, fi1);                       // col 1
        __syncthreads();
        #pragma unroll
        for (int k = 0; k < 8; ++k)
            vs[(base + k * 8 + q) * 33 + c] = make_float4(fr0[k], fi0[k], fr1[k], fi1[k]);
        __syncthreads();

        // out row k1sel + 64*k2: own V[k2] + partner V_{1-ab}[63-k2]
        float* op = ob + (size_t)k1sel * HID + (size_t)(pc * 128 + 4 * c);
        #pragma unroll
        for (int kh = 0; kh < 8; ++kh) {
            const float4 pv = vs[((64 - base) + (7 - kh) * 8 + (7 - q)) * 33 + c];
            const int k2 = q + 8 * kh;
            nv4 o;
            o.x = (fr0[kh] + pv.x) * scale;
            o.y = (fi0[kh] + pv.y) * scale;
            o.z = (fr1[kh] + pv.z) * scale;
            o.w = (fi1[kh] + pv.w) * scale;
            __builtin_nontemporal_store(o, (nv4*)(op + (size_t)(64 * k2) * HID));
        }
    } else {
        const int s  = idx - 248;
        const int k1 = (s >> 2) * 32;         // 0 or 32
        const int pc = s & 3;                 // 128-pair chunk
        const int q  = t >> 6;
        const int c  = t & 63;                // h2x2 column (2 pairs)
        const int p  = pc * 128 + 2 * c;
        // k1-major slab
        const __half2* up = ub + (size_t)(64 * k1) * 512 + p;
        h2x2 raw[8];
        #pragma unroll
        for (int a = 0; a < 8; ++a)
            raw[a] = *(const h2x2*)(up + (size_t)(8 * a + q) * 512);

        float wq_s, wq_c;
        __sincosf(-0.09817477042468103f * (float)q, &wq_s, &wq_c);
        #pragma unroll
        for (int a = 0; a < 8; ++a) {
            const float2 v = __half22float2(raw[a].a);
            fr0[a] = v.x;  fi0[a] = v.y;
        }
        fft8(fr0, fi0);
        twiddle_chain(fr0, fi0, wq_c, wq_s);
        #pragma unroll
        for (int a = 0; a < 8; ++a) {
            const float2 v = __half22float2(raw[a].b);
            fr1[a] = v.x;  fi1[a] = v.y;
        }
        fft8(fr1, fi1);
        twiddle_chain(fr1, fi1, wq_c, wq_s);

        #pragma unroll
        for (int k = 0; k < 8; ++k)
            vs[(k * 8 + q) * 65 + c] = make_float4(fr0[k], fi0[k], fr1[k], fi1[k]);
        __syncthreads();
        float4 rw[8];
        #pragma unroll
        for (int r = 0; r < 8; ++r) rw[r] = vs[(q * 8 + r) * 65 + c];
        #pragma unroll
        for (int a = 0; a < 8; ++a) { fr0[a] = rw[a].x; fi0[a] = rw[a].y; }
        fft8(fr0, fi0);
        #pragma unroll
        for (int a = 0; a < 8; ++a) { fr1[a] = rw[a].z; fi1[a] = rw[a].w; }
        fft8(fr1, fi1);
        __syncthreads();
        #pragma unroll
        for (int k = 0; k < 8; ++k)
            vs[(k * 8 + q) * 65 + c] = make_float4(fr0[k], fi0[k], fr1[k], fi1[k]);
        __syncthreads();

        // partner index: k1==0 -> (64-k2)%64, k1==32 -> 63-k2
        const int q2 = (k1 == 0) ? ((8 - q) & 7) : (7 - q);
        float* op = ob + (size_t)k1 * HID + (size_t)(pc * 256 + 4 * c);
        #pragma unroll
        for (int kh = 0; kh < 8; ++kh) {
            const int kh2 = (k1 == 0 && q == 0) ? ((8 - kh) & 7) : (7 - kh);
            const float4 pv = vs[(kh2 * 8 + q2) * 65 + c];
            const int k2 = q + 8 * kh;
            nv4 o;
            o.x = (fr0[kh] + pv.x) * scale;
            o.y = (fi0[kh] + pv.y) * scale;
            o.z = (fr1[kh] + pv.z) * scale;
            o.w = (fi1[kh] + pv.w) * scale;
            __builtin_nontemporal_store(o, (nv4*)(op + (size_t)(64 * k2) * HID));
        }
    }
}

// ---------------- fp32 in-place fallback (round-2 kernels, unchanged) ----------------

template <int MC>
__device__ __forceinline__ void fft64_lds(float* re, float* im, int off, int stride, int mbase) {
    #pragma unroll
    for (int s = 0; s < 3; ++s) {
        const int L = 1 << (2 * s);
        const float ang = -6.283185307179586f / (float)(4 * L);
        #pragma unroll
        for (int mi = 0; mi < MC; ++mi) {
            const int m  = mbase + mi;
            const int j  = m & (L - 1);
            const int i0 = ((m >> (2 * s)) << (2 * s + 2)) + j;
            const int a0 = (i0        ) * stride + off;
            const int a1 = (i0 +     L) * stride + off;
            const int a2 = (i0 + 2 * L) * stride + off;
            const int a3 = (i0 + 3 * L) * stride + off;
            const float e0x = re[a0], e0y = im[a0];
            const float e1x = re[a1], e1y = im[a1];
            const float e2x = re[a2], e2y = im[a2];
            const float e3x = re[a3], e3y = im[a3];
            float w1s, w1c;
            __sincosf(ang * (float)j, &w1s, &w1c);
            const float w2c = w1c * w1c - w1s * w1s, w2s = 2.f * w1c * w1s;
            const float w3c = w2c * w1c - w2s * w1s, w3s = w2c * w1s + w2s * w1c;
            const float t1x = e1x * w1c - e1y * w1s, t1y = e1x * w1s + e1y * w1c;
            const float t2x = e2x * w2c - e2y * w2s, t2y = e2x * w2s + e2y * w2c;
            const float t3x = e3x * w3c - e3y * w3s, t3y = e3x * w3s + e3y * w3c;
            const float a02x = e0x + t2x, a02y = e0y + t2y;
            const float s02x = e0x - t2x, s02y = e0y - t2y;
            const float a13x = t1x + t3x, a13y = t1y + t3y;
            const float s13x = t1x - t3x, s13y = t1y - t3y;
            re[a0] = a02x + a13x;  im[a0] = a02y + a13y;
            re[a1] = s02x + s13y;  im[a1] = s02y - s13x;
            re[a2] = a02x - a13x;  im[a2] = a02y - a13y;
            re[a3] = s02x - s13y;  im[a3] = s02y + s13x;
        }
        __syncthreads();
    }
}

__global__ __launch_bounds__(256) void fft_pass1(const float* __restrict__ x,
                                                 float* __restrict__ out) {
    __shared__ float sre[64 * 65];
    __shared__ float sim[64 * 65];
    const int t  = threadIdx.x;
    const int pc = blockIdx.x & 7;
    const int n2 = (blockIdx.x >> 3) & 63;
    const int b  = blockIdx.x >> 9;
    const float* xb = x   + (size_t)b * SEQ * HID + pc * 128;
    float*       ob = out + (size_t)b * SEQ * HID + pc * 128;

    const int c  = t & 31;
    const int r0 = t >> 5;
    #pragma unroll
    for (int i = 0; i < 8; ++i) {
        const int r  = r0 + 8 * i;
        const float4 f = *(const float4*)(xb + (size_t)(n2 + 64 * r) * HID + 4 * c);
        const int rr = rev4_3(r);
        sre[rr * 65 + 2 * c]     = f.x;  sim[rr * 65 + 2 * c]     = f.y;
        sre[rr * 65 + 2 * c + 1] = f.z;  sim[rr * 65 + 2 * c + 1] = f.w;
    }
    __syncthreads();

    fft64_lds<4>(sre, sim, t & 63, 65, 4 * (t >> 6));

    const float tw = -1.5339807878856412e-3f;
    #pragma unroll
    for (int i = 0; i < 8; ++i) {
        const int k1 = r0 + 8 * i;
        float ws, wc;
        __sincosf(tw * (float)(n2 * k1), &ws, &wc);
        const float ar = sre[k1 * 65 + 2 * c],     ai = sim[k1 * 65 + 2 * c];
        const float br = sre[k1 * 65 + 2 * c + 1], bi = sim[k1 * 65 + 2 * c + 1];
        float4 f;
        f.x = ar * wc - ai * ws;  f.y = ar * ws + ai * wc;
        f.z = br * wc - bi * ws;  f.w = br * ws + bi * wc;
        *(float4*)(ob + (size_t)(64 * n2 + k1) * HID + 4 * c) = f;
    }
}

__global__ __launch_bounds__(256) void fft_pass2(float* out) {
    __shared__ float lds[8448];
    const int t   = threadIdx.x;
    const int b   = blockIdx.x >> 9;
    const int idx = blockIdx.x & 511;
    float* ob = out + (size_t)b * SEQ * HID;
    const float scale = 1.0f / 128.0f;

    if (idx < 496) {
        const int k1 = 1 + (idx >> 4);
        const int pc = idx & 15;
        float* are = lds;          float* aim = lds + 2112;
        float* bre = lds + 4224;   float* bim = lds + 6336;
        const int c  = t & 15;
        const int rg = t >> 4;
        #pragma unroll
        for (int i = 0; i < 4; ++i) {
            const int n2 = rg + 16 * i;
            const int rr = rev4_3(n2);
            const float4 fa = *(const float4*)(ob + (size_t)(64 * n2 + k1)      * HID + pc * 64 + 4 * c);
            const float4 fb = *(const float4*)(ob + (size_t)(64 * n2 + 64 - k1) * HID + pc * 64 + 4 * c);
            are[rr * 33 + 2 * c]     = fa.x;  aim[rr * 33 + 2 * c]     = fa.y;
            are[rr * 33 + 2 * c + 1] = fa.z;  aim[rr * 33 + 2 * c + 1] = fa.w;
            bre[rr * 33 + 2 * c]     = fb.x;  bim[rr * 33 + 2 * c]     = fb.y;
            bre[rr * 33 + 2 * c + 1] = fb.z;  bim[rr * 33 + 2 * c + 1] = fb.w;
        }
        __syncthreads();

        const int lane = t & 63;
        float* fre = lds + 4224 * (lane >> 5);
        fft64_lds<4>(fre, fre + 2112, lane & 31, 33, 4 * (t >> 6));

        #pragma unroll
        for (int i = 0; i < 4; ++i) {
            const int k2 = rg + 16 * i;
            const int q  = 63 - k2;
            float4 f, g;
            f.x = (are[k2 * 33 + 2 * c]     + bre[q * 33 + 2 * c])     * scale;
            f.y = (aim[k2 * 33 + 2 * c]     + bim[q * 33 + 2 * c])     * scale;
            f.z = (are[k2 * 33 + 2 * c + 1] + bre[q * 33 + 2 * c + 1]) * scale;
            f.w = (aim[k2 * 33 + 2 * c + 1] + bim[q * 33 + 2 * c + 1]) * scale;
            *(float4*)(ob + (size_t)(k1 + 64 * k2)      * HID + pc * 64 + 4 * c) = f;
            g.x = (bre[k2 * 33 + 2 * c]     + are[q * 33 + 2 * c])     * scale;
            g.y = (bim[k2 * 33 + 2 * c]     + aim[q * 33 + 2 * c])     * scale;
            g.z = (bre[k2 * 33 + 2 * c + 1] + are[q * 33 + 2 * c + 1]) * scale;
            g.w = (bim[k2 * 33 + 2 * c + 1] + aim[q * 33 + 2 * c + 1]) * scale;
            *(float4*)(ob + (size_t)(64 - k1 + 64 * k2) * HID + pc * 64 + 4 * c) = g;
        }
    } else {
        const int s  = idx - 496;
        const int k1 = (s >> 3) * 32;
        const int pc = s & 7;
        float* sre = lds;
        float* sim = lds + 4160;
        const int c  = t & 31;
        const int rg = t >> 5;
        #pragma unroll
        for (int i = 0; i < 8; ++i) {
            const int n2 = rg + 8 * i;
            const int rr = rev4_3(n2);
            const float4 f = *(const float4*)(ob + (size_t)(64 * n2 + k1) * HID + pc * 128 + 4 * c);
            sre[rr * 65 + 2 * c]     = f.x;  sim[rr * 65 + 2 * c]     = f.y;
            sre[rr * 65 + 2 * c + 1] = f.z;  sim[rr * 65 + 2 * c + 1] = f.w;
        }
        __syncthreads();

        fft64_lds<4>(sre, sim, t & 63, 65, 4 * (t >> 6));

        #pragma unroll
        for (int i = 0; i < 8; ++i) {
            const int k2 = rg + 8 * i;
            const int q  = (k1 == 0) ? ((64 - k2) & 63) : (63 - k2);
            float4 f;
            f.x = (sre[k2 * 65 + 2 * c]     + sre[q * 65 + 2 * c])     * scale;
            f.y = (sim[k2 * 65 + 2 * c]     + sim[q * 65 + 2 * c])     * scale;
            f.z = (sre[k2 * 65 + 2 * c + 1] + sre[q * 65 + 2 * c + 1]) * scale;
            f.w = (sim[k2 * 65 + 2 * c + 1] + sim[q * 65 + 2 * c + 1]) * scale;
            *(float4*)(ob + (size_t)(k1 + 64 * k2) * HID + pc * 128 + 4 * c) = f;
        }
    }
}

extern "C" void kernel_launch(void* const* d_in, const int* in_sizes, int n_in,
                              void* d_out, int out_size, void* d_ws, size_t ws_size,
                              hipStream_t stream) {
    const float* x = (const float*)d_in[0];
    float* out = (float*)d_out;
    const size_t need = (size_t)8 * SEQ * 512 * sizeof(__half2);   // 64 MiB
    if (ws_size >= need) {
        __half2* u = (__half2*)d_ws;
        fft_pass1_x2<<<dim3(8 * 64 * 4), dim3(512), 0, stream>>>(x, u);
        fft_pass2_x2<<<dim3(8 * 256), dim3(512), 0, stream>>>(u, out);
    } else {
        fft_pass1<<<dim3(8 * 64 * 8), dim3(256), 0, stream>>>(x, out);
        fft_pass2<<<dim3(8 * 512), dim3(256), 0, stream>>>(out);
    }
}